// Round 1
// 1293.767 us; speedup vs baseline: 1.0893x; 1.0893x over previous
//
#include <hip/hip_runtime.h>

typedef unsigned short u16;
typedef unsigned int u32;
using u16x4 = __attribute__((ext_vector_type(4))) u16;
using u16x8 = __attribute__((ext_vector_type(8))) u16;
using bf16x8 = __attribute__((ext_vector_type(8))) __bf16;
using f32x4 = __attribute__((ext_vector_type(4))) float;

#define B_ 8
#define T_ 2048
#define C_ 768
#define E_ 8
#define K_ 2
#define H_ 3072
#define CAP_ 640
#define M_ (B_ * CAP_) /* 5120 rows per expert */
#define HC_ 1024       /* H chunk: S_chunk = E*M*HC bf16 = 83.9 MB */
#define NCHUNK_ (H_ / HC_)
#define OVF_MAX_ 32768

__device__ __forceinline__ u16 f2bf(float x) {
  u32 u = __float_as_uint(x);
  u32 r = (u + 0x7FFFu + ((u >> 16) & 1u)) >> 16;  // RNE
  return (u16)r;
}
__device__ __forceinline__ float bf2f(u16 v) { return __uint_as_float(((u32)v) << 16); }

__device__ __forceinline__ void gl_lds16(const u16* g, u16* l) {
  __builtin_amdgcn_global_load_lds((const __attribute__((address_space(1))) u32*)g,
                                   (__attribute__((address_space(3))) u32*)l, 16, 0, 0);
}
__device__ __forceinline__ bf16x8 ldfrag(const u16* p) {
  return __builtin_bit_cast(bf16x8, *(const u16x8*)p);
}

// ---------- weight fp32 -> bf16 transpose:  in [E][R][Cc] -> out [E][Cc][R] ----------
__global__ void wconv_transpose(const float* __restrict__ in, u16* __restrict__ out,
                                int R, int Cc) {
  __shared__ float tile[32][33];
  const float* inE = in + (size_t)blockIdx.z * R * Cc;
  u16* outE = out + (size_t)blockIdx.z * R * Cc;
  int tx = threadIdx.x & 31, ty = threadIdx.x >> 5;  // 32 x 8
  int r0 = blockIdx.y * 32, c0 = blockIdx.x * 32;
#pragma unroll
  for (int j = 0; j < 4; j++)
    tile[ty + j * 8][tx] = inE[(size_t)(r0 + ty + j * 8) * Cc + (c0 + tx)];
  __syncthreads();
#pragma unroll
  for (int j = 0; j < 4; j++)
    outE[(size_t)(c0 + ty + j * 8) * R + (r0 + tx)] = f2bf(tile[tx][ty + j * 8]);
}

// ---------- router: logits, softmax, top-2 (fp64 accumulate; tie -> lower index) ----------
__global__ void router_kernel(const float* __restrict__ x, const float* __restrict__ wr,
                              const float* __restrict__ br, float* __restrict__ tkp,
                              int* __restrict__ tki) {
  int bt = (blockIdx.x << 2) | (threadIdx.x >> 6);  // token index b*T+t
  int lane = threadIdx.x & 63;
  const float* xr = x + (size_t)bt * C_;
  double acc[E_];
#pragma unroll
  for (int e = 0; e < E_; e++) acc[e] = 0.0;
#pragma unroll
  for (int i = 0; i < C_ / 64; i++) {
    int c = lane + i * 64;
    float xv = xr[c];
    const float* w = wr + c * E_;
#pragma unroll
    for (int e = 0; e < E_; e++) acc[e] += (double)xv * (double)w[e];
  }
#pragma unroll
  for (int off = 32; off > 0; off >>= 1) {
#pragma unroll
    for (int e = 0; e < E_; e++) acc[e] += __shfl_xor(acc[e], off);
  }
  if (lane == 0) {
    double lg[E_];
#pragma unroll
    for (int e = 0; e < E_; e++) lg[e] = acc[e] + (double)br[e];
    int i0 = 0;
#pragma unroll
    for (int e = 1; e < E_; e++) if (lg[e] > lg[i0]) i0 = e;
    int i1 = (i0 == 0) ? 1 : 0;
#pragma unroll
    for (int e = 0; e < E_; e++) if (e != i0 && lg[e] > lg[i1]) i1 = e;
    double mx = lg[i0], s = 0.0, pv[E_];
#pragma unroll
    for (int e = 0; e < E_; e++) { pv[e] = exp(lg[e] - mx); s += pv[e]; }
    tkp[bt * 2 + 0] = (float)(pv[i0] / s);
    tkp[bt * 2 + 1] = (float)(pv[i1] / s);
    tki[bt * 2 + 0] = i0;
    tki[bt * 2 + 1] = i1;
  }
}

// ---------- slot positions: parallel 8-way counted scan, one block per b ----------
__global__ void pos_kernel(const int* __restrict__ tki, int* __restrict__ pos) {
  __shared__ int sc[256][9];  // +1 pad: avoid 8-way bank conflict
  int b = blockIdx.x;
  int tid = threadIdx.x;
  const int* tib = tki + (size_t)b * T_ * 2;
  int* pb = pos + (size_t)b * T_ * 2;
  int ids[16];
  int cnt[E_];
#pragma unroll
  for (int e = 0; e < E_; e++) cnt[e] = 0;
#pragma unroll
  for (int j = 0; j < 16; j++) {
    int i = tid * 16 + j;
    int k = i >> 11, t = i & (T_ - 1);  // k-major
    int id = tib[t * 2 + k];
    ids[j] = id;
#pragma unroll
    for (int e = 0; e < E_; e++) cnt[e] += (id == e);
  }
#pragma unroll
  for (int e = 0; e < E_; e++) sc[tid][e] = cnt[e];
  __syncthreads();
  for (int off = 1; off < 256; off <<= 1) {
    int v[E_];
    if (tid >= off) {
#pragma unroll
      for (int e = 0; e < E_; e++) v[e] = sc[tid - off][e];
    }
    __syncthreads();
    if (tid >= off) {
#pragma unroll
      for (int e = 0; e < E_; e++) sc[tid][e] += v[e];
    }
    __syncthreads();
  }
  int base[E_];
#pragma unroll
  for (int e = 0; e < E_; e++) base[e] = (tid > 0) ? sc[tid - 1][e] : 0;
#pragma unroll
  for (int j = 0; j < 16; j++) {
    int i = tid * 16 + j;
    int k = i >> 11, t = i & (T_ - 1);
    int id = ids[j];
    int p = 0;
#pragma unroll
    for (int e = 0; e < E_; e++) p += (id == e) ? base[e] : 0;
    pb[t * 2 + k] = p;
#pragma unroll
    for (int e = 0; e < E_; e++) base[e] += (id == e);
  }
}

// ---------- clear inverse map + overflow counter (must precede dispatch) ----------
__global__ void clear_kernel(int* __restrict__ invt, int* __restrict__ ovfCnt) {
  int i = blockIdx.x * 256 + threadIdx.x;  // grid covers exactly E_*M_
  invt[i] = -1;
  if (i == 0) *ovfCnt = 0;
}

// ---------- dispatch: x row -> bf16 expert buffer [E][M_][C_] + inverse slot->token map ----------
__global__ void dispatch_kernel(const float* __restrict__ x, const int* __restrict__ tki,
                                const int* __restrict__ pos, u16* __restrict__ Xd,
                                int* __restrict__ invt, int* __restrict__ ovfCnt,
                                int2* __restrict__ ovf) {
  int gw = (blockIdx.x << 2) | (threadIdx.x >> 6);  // (b*T+t)*2 + k
  int lane = threadIdx.x & 63;
  int bt = gw >> 1;
  int b = bt >> 11;
  int e = tki[gw];
  int p = pos[gw];
  if (p >= CAP_) {  // capacity drop: record for exact clamp-gather handling
    if (lane == 0) {
      int idx = atomicAdd(ovfCnt, 1);
      if (idx < OVF_MAX_) ovf[idx] = make_int2(bt, gw & 1);
    }
    return;
  }
  size_t row = (size_t)e * M_ + (size_t)b * CAP_ + p;
  if (lane == 0) invt[row] = gw;  // owner (token,slot) of this expert row
  const f32x4* src = (const f32x4*)(x + (size_t)bt * C_);
  u16* dst = Xd + row * C_;
#pragma unroll
  for (int i = 0; i < 3; i++) {
    f32x4 v = src[lane + i * 64];
    u16x4 o;
    o.x = f2bf(v.x); o.y = f2bf(v.y); o.z = f2bf(v.z); o.w = f2bf(v.w);
    *(u16x4*)(dst + (size_t)(lane + i * 64) * 4) = o;
  }
}

// ---------- out init: out[bt] = w0*bp[e0] + w1*bp[e1] (proj bias, pre-added once) ----------
__global__ void init_out_kernel(const float* __restrict__ tkp, const int* __restrict__ tki,
                                const float* __restrict__ bp, float* __restrict__ out) {
  int bt = (blockIdx.x << 2) | (threadIdx.x >> 6);
  int lane = threadIdx.x & 63;
  int e0 = tki[bt * 2], e1 = tki[bt * 2 + 1];
  float w0 = tkp[bt * 2], w1 = tkp[bt * 2 + 1];
  const f32x4* b0 = (const f32x4*)(bp + (size_t)e0 * C_);
  const f32x4* b1 = (const f32x4*)(bp + (size_t)e1 * C_);
  f32x4* orow = (f32x4*)(out + (size_t)bt * C_);
#pragma unroll
  for (int i = 0; i < 3; i++) {
    int c = lane + i * 64;
    orow[c] = w0 * b0[c] + w1 * b1[c];
  }
}

// ---------- GEMM1 (H-chunked, all experts): S_chunk = silu((X@Wfc+bfc)*(X@Wg+bg)) ----------
// grid = E * 40 * (HC_/128) = 2560 blocks -> ~10 blocks/CU
__global__ __launch_bounds__(256, 2) void gemm_fc_gate(
    const u16* __restrict__ Xd, const u16* __restrict__ WfcT, const u16* __restrict__ WgT,
    const float* __restrict__ bfc, const float* __restrict__ bg, u16* __restrict__ S,
    int hc) {
  __shared__ __align__(16) u16 Alds[128 * 32];
  __shared__ __align__(16) u16 B1lds[128 * 32];
  __shared__ __align__(16) u16 B2lds[128 * 32];
  int bid = blockIdx.x;
  int e = bid / (40 * (HC_ / 128));
  int t = bid % (40 * (HC_ / 128));
  int tm = t / (HC_ / 128), tn = t % (HC_ / 128);
  int tid = threadIdx.x;
  int lane = tid & 63, wv = tid >> 6;
  int wm = wv & 1, wn = wv >> 1;
  int lr = lane & 15, quad = lane >> 4;

  const u16* XdE = Xd + (size_t)e * M_ * C_;
  const u16* B1E = WfcT + ((size_t)e * H_ + (size_t)hc * HC_) * C_;  // [H][C] rows within chunk
  const u16* B2E = WgT + ((size_t)e * H_ + (size_t)hc * HC_) * C_;

  int rhalf = tid >> 2;  // 0..63
  int chunk = tid & 3;
  const u16* gA0 = XdE + (size_t)(tm * 128 + rhalf) * C_ + chunk * 8;
  const u16* gA1 = gA0 + 64 * C_;
  const u16* gB10 = B1E + (size_t)(tn * 128 + rhalf) * C_ + chunk * 8;
  const u16* gB11 = gB10 + 64 * C_;
  const u16* gB20 = B2E + (size_t)(tn * 128 + rhalf) * C_ + chunk * 8;
  const u16* gB21 = gB20 + 64 * C_;
  u16* lA0 = Alds + (wv * 16) * 32;
  u16* lA1 = Alds + (64 + wv * 16) * 32;
  u16* lB10 = B1lds + (wv * 16) * 32;
  u16* lB11 = B1lds + (64 + wv * 16) * 32;
  u16* lB20 = B2lds + (wv * 16) * 32;
  u16* lB21 = B2lds + (64 + wv * 16) * 32;

  f32x4 acc1[4][4], acc2[4][4];
#pragma unroll
  for (int i = 0; i < 4; i++)
#pragma unroll
    for (int j = 0; j < 4; j++) {
      acc1[i][j] = (f32x4){0.f, 0.f, 0.f, 0.f};
      acc2[i][j] = (f32x4){0.f, 0.f, 0.f, 0.f};
    }

  for (int kt = 0; kt < C_ / 32; kt++) {
    int ko = kt * 32;
    __syncthreads();
    gl_lds16(gA0 + ko, lA0);
    gl_lds16(gA1 + ko, lA1);
    gl_lds16(gB10 + ko, lB10);
    gl_lds16(gB11 + ko, lB11);
    gl_lds16(gB20 + ko, lB20);
    gl_lds16(gB21 + ko, lB21);
    __syncthreads();
    bf16x8 af[4], b1f[4], b2f[4];
#pragma unroll
    for (int i = 0; i < 4; i++) {
      af[i] = ldfrag(Alds + (wm * 64 + i * 16 + lr) * 32 + quad * 8);
      b1f[i] = ldfrag(B1lds + (wn * 64 + i * 16 + lr) * 32 + quad * 8);
      b2f[i] = ldfrag(B2lds + (wn * 64 + i * 16 + lr) * 32 + quad * 8);
    }
#pragma unroll
    for (int i = 0; i < 4; i++)
#pragma unroll
      for (int j = 0; j < 4; j++) {
        acc1[i][j] = __builtin_amdgcn_mfma_f32_16x16x32_bf16(af[i], b1f[j], acc1[i][j], 0, 0, 0);
        acc2[i][j] = __builtin_amdgcn_mfma_f32_16x16x32_bf16(af[i], b2f[j], acc2[i][j], 0, 0, 0);
      }
  }

  u16* Se = S + (size_t)e * M_ * HC_;
  const float* bfcE = bfc + (size_t)e * H_ + (size_t)hc * HC_;
  const float* bgE = bg + (size_t)e * H_ + (size_t)hc * HC_;
  int col0 = tn * 128 + wn * 64 + lr;  // local column within chunk
  int row0 = tm * 128 + wm * 64 + quad * 4;
#pragma unroll
  for (int j = 0; j < 4; j++) {
    int col = col0 + j * 16;
    float bf_ = bfcE[col], bg_ = bgE[col];
#pragma unroll
    for (int i = 0; i < 4; i++) {
      int row = row0 + i * 16;
#pragma unroll
      for (int r = 0; r < 4; r++) {
        float h = acc1[i][j][r] + bf_;
        float g = acc2[i][j][r] + bg_;
        float z = h * g;
        float sv = z / (1.f + __expf(-z));  // silu
        Se[(size_t)(row + r) * HC_ + col] = f2bf(sv);
      }
    }
  }
}

// ---------- GEMM2 (H-chunked, all experts): partial O scatter-added into out ----------
// grid = E * 40 * 6 = 1920 blocks -> ~7.5 blocks/CU. K = HC_ per chunk.
__global__ __launch_bounds__(256, 2) void gemm_proj_scatter(
    const u16* __restrict__ S, const u16* __restrict__ WpT,
    const int* __restrict__ invt, const float* __restrict__ tkp,
    const int* __restrict__ tki, const int* __restrict__ ovfCnt,
    const int2* __restrict__ ovf, float* __restrict__ out, int hc) {
  __shared__ __align__(16) u16 Alds[128 * 32];
  __shared__ __align__(16) u16 Blds[128 * 32];
  int bid = blockIdx.x;
  int e = bid / (40 * 6);
  int t = bid % (40 * 6);
  int tm = t / 6, tn = t % 6;
  int tid = threadIdx.x;
  int lane = tid & 63, wv = tid >> 6;
  int wm = wv & 1, wn = wv >> 1;
  int lr = lane & 15, quad = lane >> 4;

  const u16* SE = S + (size_t)e * M_ * HC_;                     // [M][HC] rows
  const u16* BE = WpT + (size_t)e * C_ * H_ + (size_t)hc * HC_; // [C][H], k-offset into chunk

  int rhalf = tid >> 2;
  int chunk = tid & 3;
  const u16* gA0 = SE + (size_t)(tm * 128 + rhalf) * HC_ + chunk * 8;
  const u16* gA1 = gA0 + 64 * HC_;
  const u16* gB0 = BE + (size_t)(tn * 128 + rhalf) * H_ + chunk * 8;
  const u16* gB1 = gB0 + 64 * H_;
  u16* lA0 = Alds + (wv * 16) * 32;
  u16* lA1 = Alds + (64 + wv * 16) * 32;
  u16* lB0 = Blds + (wv * 16) * 32;
  u16* lB1 = Blds + (64 + wv * 16) * 32;

  f32x4 acc[4][4];
#pragma unroll
  for (int i = 0; i < 4; i++)
#pragma unroll
    for (int j = 0; j < 4; j++) acc[i][j] = (f32x4){0.f, 0.f, 0.f, 0.f};

  for (int kt = 0; kt < HC_ / 32; kt++) {
    int ko = kt * 32;
    __syncthreads();
    gl_lds16(gA0 + ko, lA0);
    gl_lds16(gA1 + ko, lA1);
    gl_lds16(gB0 + ko, lB0);
    gl_lds16(gB1 + ko, lB1);
    __syncthreads();
    bf16x8 af[4], bf[4];
#pragma unroll
    for (int i = 0; i < 4; i++) {
      af[i] = ldfrag(Alds + (wm * 64 + i * 16 + lr) * 32 + quad * 8);
      bf[i] = ldfrag(Blds + (wn * 64 + i * 16 + lr) * 32 + quad * 8);
    }
#pragma unroll
    for (int i = 0; i < 4; i++)
#pragma unroll
      for (int j = 0; j < 4; j++)
        acc[i][j] = __builtin_amdgcn_mfma_f32_16x16x32_bf16(af[i], bf[j], acc[i][j], 0, 0, 0);
  }

  // epilogue: weighted scatter-add into out (bias already in out via init_out)
  int col0 = tn * 128 + wn * 64 + lr;
  int row0 = tm * 128 + wm * 64 + quad * 4;
  const int* invtE = invt + e * M_;
#pragma unroll
  for (int i = 0; i < 4; i++) {
#pragma unroll
    for (int r = 0; r < 4; r++) {
      int re = row0 + i * 16 + r;
      int g = invtE[re];  // row-uniform per quad -> branch is quad-uniform
      if (g >= 0) {
        float w = tkp[g];
        float* orow = out + (size_t)(g >> 1) * C_;
#pragma unroll
        for (int j = 0; j < 4; j++)
          atomicAdd(orow + col0 + j * 16, w * acc[i][j][r]);
      }
    }
  }
  // dropped tokens gather clamped row CAP_-1 (jax clip semantics). Blocks whose tile
  // contains row (b, CAP_-1) (tm%5==4, local row 127 -> wm=1,quad=3,i=3,r=3) also add
  // that row's partial for each matching overflow entry. n==0 in practice.
  if (wm == 1 && quad == 3 && (tm % 5) == 4) {
    int b = tm / 5;
    int nov = *ovfCnt;
    if (nov > OVF_MAX_) nov = OVF_MAX_;
    for (int o = 0; o < nov; o++) {
      int2 en = ovf[o];
      int gw2 = en.x * 2 + en.y;
      if (tki[gw2] == e && (en.x >> 11) == b) {
        float w = tkp[gw2];
        float* orow = out + (size_t)en.x * C_;
#pragma unroll
        for (int j = 0; j < 4; j++)
          atomicAdd(orow + col0 + j * 16, w * acc[3][j][3]);
      }
    }
  }
}

extern "C" void kernel_launch(void* const* d_in, const int* in_sizes, int n_in,
                              void* d_out, int out_size, void* d_ws, size_t ws_size,
                              hipStream_t stream) {
  (void)in_sizes; (void)n_in; (void)out_size; (void)ws_size;
  const float* x = (const float*)d_in[0];
  const float* w_router = (const float*)d_in[1];
  const float* b_router = (const float*)d_in[2];
  const float* w_c_fc = (const float*)d_in[3];
  const float* b_c_fc = (const float*)d_in[4];
  const float* w_gate = (const float*)d_in[5];
  const float* b_gate = (const float*)d_in[6];
  const float* w_c_proj = (const float*)d_in[7];
  const float* b_c_proj = (const float*)d_in[8];
  float* out = (float*)d_out;

  char* p = (char*)d_ws;
  auto alloc = [&](size_t n) { char* r = p; p += (n + 255) & ~(size_t)255; return r; };
  const size_t WN = (size_t)E_ * C_ * H_;
  u16* WfcT = (u16*)alloc(WN * 2);
  u16* WgT = (u16*)alloc(WN * 2);
  u16* WpT = (u16*)alloc(WN * 2);
  u16* Xd = (u16*)alloc((size_t)E_ * M_ * C_ * 2);
  float* tkp = (float*)alloc((size_t)B_ * T_ * 2 * 4);
  int* tki = (int*)alloc((size_t)B_ * T_ * 2 * 4);
  int* pos = (int*)alloc((size_t)B_ * T_ * 2 * 4);
  int* invt = (int*)alloc((size_t)E_ * M_ * 4);
  int* ovfCnt = (int*)alloc(4);
  int2* ovf = (int2*)alloc((size_t)OVF_MAX_ * 8);
  u16* S = (u16*)alloc((size_t)E_ * M_ * HC_ * 2);
  // total ~260.9 MB; previous g=1 layout proved ws >= 270.9 MB, so this fits.

  dim3 blk(256);
  // weights -> bf16, transposed to [N][K]
  wconv_transpose<<<dim3(H_ / 32, C_ / 32, E_), blk, 0, stream>>>(w_c_fc, WfcT, C_, H_);
  wconv_transpose<<<dim3(H_ / 32, C_ / 32, E_), blk, 0, stream>>>(w_gate, WgT, C_, H_);
  wconv_transpose<<<dim3(C_ / 32, H_ / 32, E_), blk, 0, stream>>>(w_c_proj, WpT, H_, C_);

  router_kernel<<<dim3(B_ * T_ / 4), blk, 0, stream>>>(x, w_router, b_router, tkp, tki);
  pos_kernel<<<dim3(B_), blk, 0, stream>>>(tki, pos);
  clear_kernel<<<dim3(E_ * M_ / 256), blk, 0, stream>>>(invt, ovfCnt);
  dispatch_kernel<<<dim3(B_ * T_ * K_ / 4), blk, 0, stream>>>(x, tki, pos, Xd, invt, ovfCnt, ovf);
  init_out_kernel<<<dim3(B_ * T_ / 4), blk, 0, stream>>>(tkp, tki, b_c_proj, out);

  // H-chunked grouped GEMMs: every dispatch spans all 8 experts (2560 / 1920 blocks)
  for (int hc = 0; hc < NCHUNK_; hc++) {
    gemm_fc_gate<<<dim3(E_ * 40 * (HC_ / 128)), blk, 0, stream>>>(
        Xd, WfcT, WgT, b_c_fc, b_gate, S, hc);
    gemm_proj_scatter<<<dim3(E_ * 40 * 6), blk, 0, stream>>>(
        S, WpT, invt, tkp, tki, ovfCnt, ovf, out, hc);
  }
}

// Round 2
// 1150.406 us; speedup vs baseline: 1.2250x; 1.1246x over previous
//
#include <hip/hip_runtime.h>

typedef unsigned short u16;
typedef unsigned int u32;
using u16x4 = __attribute__((ext_vector_type(4))) u16;
using u16x8 = __attribute__((ext_vector_type(8))) u16;
using bf16x8 = __attribute__((ext_vector_type(8))) __bf16;
using f32x4 = __attribute__((ext_vector_type(4))) float;

#define B_ 8
#define T_ 2048
#define C_ 768
#define E_ 8
#define K_ 2
#define H_ 3072
#define CAP_ 640
#define M_ (B_ * CAP_) /* 5120 rows per expert */
#define HC_ 1024       /* H chunk: S_chunk = E*M*HC bf16 = 83.9 MB */
#define NCHUNK_ (H_ / HC_)
#define OVF_MAX_ 32768

__device__ __forceinline__ u16 f2bf(float x) {
  u32 u = __float_as_uint(x);
  u32 r = (u + 0x7FFFu + ((u >> 16) & 1u)) >> 16;  // RNE
  return (u16)r;
}
__device__ __forceinline__ float bf2f(u16 v) { return __uint_as_float(((u32)v) << 16); }

__device__ __forceinline__ void gl_lds16(const u16* g, u16* l) {
  __builtin_amdgcn_global_load_lds((const __attribute__((address_space(1))) u32*)g,
                                   (__attribute__((address_space(3))) u32*)l, 16, 0, 0);
}
__device__ __forceinline__ bf16x8 ldfrag(const u16* p) {
  return __builtin_bit_cast(bf16x8, *(const u16x8*)p);
}

// ---------- weight fp32 -> bf16 transpose:  in [E][R][Cc] -> out [E][Cc][R] ----------
__global__ void wconv_transpose(const float* __restrict__ in, u16* __restrict__ out,
                                int R, int Cc) {
  __shared__ float tile[32][33];
  const float* inE = in + (size_t)blockIdx.z * R * Cc;
  u16* outE = out + (size_t)blockIdx.z * R * Cc;
  int tx = threadIdx.x & 31, ty = threadIdx.x >> 5;  // 32 x 8
  int r0 = blockIdx.y * 32, c0 = blockIdx.x * 32;
#pragma unroll
  for (int j = 0; j < 4; j++)
    tile[ty + j * 8][tx] = inE[(size_t)(r0 + ty + j * 8) * Cc + (c0 + tx)];
  __syncthreads();
#pragma unroll
  for (int j = 0; j < 4; j++)
    outE[(size_t)(c0 + ty + j * 8) * R + (r0 + tx)] = f2bf(tile[tx][ty + j * 8]);
}

// ---------- router: logits, softmax, top-2 (fp64 accumulate; tie -> lower index) ----------
__global__ void router_kernel(const float* __restrict__ x, const float* __restrict__ wr,
                              const float* __restrict__ br, float* __restrict__ tkp,
                              int* __restrict__ tki) {
  int bt = (blockIdx.x << 2) | (threadIdx.x >> 6);  // token index b*T+t
  int lane = threadIdx.x & 63;
  const float* xr = x + (size_t)bt * C_;
  double acc[E_];
#pragma unroll
  for (int e = 0; e < E_; e++) acc[e] = 0.0;
#pragma unroll
  for (int i = 0; i < C_ / 64; i++) {
    int c = lane + i * 64;
    float xv = xr[c];
    const float* w = wr + c * E_;
#pragma unroll
    for (int e = 0; e < E_; e++) acc[e] += (double)xv * (double)w[e];
  }
#pragma unroll
  for (int off = 32; off > 0; off >>= 1) {
#pragma unroll
    for (int e = 0; e < E_; e++) acc[e] += __shfl_xor(acc[e], off);
  }
  if (lane == 0) {
    double lg[E_];
#pragma unroll
    for (int e = 0; e < E_; e++) lg[e] = acc[e] + (double)br[e];
    int i0 = 0;
#pragma unroll
    for (int e = 1; e < E_; e++) if (lg[e] > lg[i0]) i0 = e;
    int i1 = (i0 == 0) ? 1 : 0;
#pragma unroll
    for (int e = 0; e < E_; e++) if (e != i0 && lg[e] > lg[i1]) i1 = e;
    double mx = lg[i0], s = 0.0, pv[E_];
#pragma unroll
    for (int e = 0; e < E_; e++) { pv[e] = exp(lg[e] - mx); s += pv[e]; }
    tkp[bt * 2 + 0] = (float)(pv[i0] / s);
    tkp[bt * 2 + 1] = (float)(pv[i1] / s);
    tki[bt * 2 + 0] = i0;
    tki[bt * 2 + 1] = i1;
  }
}

// ---------- slot positions: parallel 8-way counted scan, one block per b ----------
__global__ void pos_kernel(const int* __restrict__ tki, int* __restrict__ pos) {
  __shared__ int sc[256][9];  // +1 pad: avoid 8-way bank conflict
  int b = blockIdx.x;
  int tid = threadIdx.x;
  const int* tib = tki + (size_t)b * T_ * 2;
  int* pb = pos + (size_t)b * T_ * 2;
  int ids[16];
  int cnt[E_];
#pragma unroll
  for (int e = 0; e < E_; e++) cnt[e] = 0;
#pragma unroll
  for (int j = 0; j < 16; j++) {
    int i = tid * 16 + j;
    int k = i >> 11, t = i & (T_ - 1);  // k-major
    int id = tib[t * 2 + k];
    ids[j] = id;
#pragma unroll
    for (int e = 0; e < E_; e++) cnt[e] += (id == e);
  }
#pragma unroll
  for (int e = 0; e < E_; e++) sc[tid][e] = cnt[e];
  __syncthreads();
  for (int off = 1; off < 256; off <<= 1) {
    int v[E_];
    if (tid >= off) {
#pragma unroll
      for (int e = 0; e < E_; e++) v[e] = sc[tid - off][e];
    }
    __syncthreads();
    if (tid >= off) {
#pragma unroll
      for (int e = 0; e < E_; e++) sc[tid][e] += v[e];
    }
    __syncthreads();
  }
  int base[E_];
#pragma unroll
  for (int e = 0; e < E_; e++) base[e] = (tid > 0) ? sc[tid - 1][e] : 0;
#pragma unroll
  for (int j = 0; j < 16; j++) {
    int i = tid * 16 + j;
    int k = i >> 11, t = i & (T_ - 1);
    int id = ids[j];
    int p = 0;
#pragma unroll
    for (int e = 0; e < E_; e++) p += (id == e) ? base[e] : 0;
    pb[t * 2 + k] = p;
#pragma unroll
    for (int e = 0; e < E_; e++) base[e] += (id == e);
  }
}

// ---------- clear inverse map + overflow counter (must precede dispatch) ----------
__global__ void clear_kernel(int* __restrict__ invt, int* __restrict__ ovfCnt) {
  int i = blockIdx.x * 256 + threadIdx.x;  // grid covers exactly E_*M_
  invt[i] = -1;
  if (i == 0) *ovfCnt = 0;
}

// ---------- dispatch: x row -> bf16 expert buffer [E][M_][C_] + inverse slot->token map ----------
__global__ void dispatch_kernel(const float* __restrict__ x, const int* __restrict__ tki,
                                const int* __restrict__ pos, u16* __restrict__ Xd,
                                int* __restrict__ invt, int* __restrict__ ovfCnt,
                                int2* __restrict__ ovf) {
  int gw = (blockIdx.x << 2) | (threadIdx.x >> 6);  // (b*T+t)*2 + k
  int lane = threadIdx.x & 63;
  int bt = gw >> 1;
  int b = bt >> 11;
  int e = tki[gw];
  int p = pos[gw];
  if (p >= CAP_) {  // capacity drop: record for exact clamp-gather handling
    if (lane == 0) {
      int idx = atomicAdd(ovfCnt, 1);
      if (idx < OVF_MAX_) ovf[idx] = make_int2(bt, gw & 1);
    }
    return;
  }
  size_t row = (size_t)e * M_ + (size_t)b * CAP_ + p;
  if (lane == 0) invt[row] = gw;  // owner (token,slot) of this expert row
  const f32x4* src = (const f32x4*)(x + (size_t)bt * C_);
  u16* dst = Xd + row * C_;
#pragma unroll
  for (int i = 0; i < 3; i++) {
    f32x4 v = src[lane + i * 64];
    u16x4 o;
    o.x = f2bf(v.x); o.y = f2bf(v.y); o.z = f2bf(v.z); o.w = f2bf(v.w);
    *(u16x4*)(dst + (size_t)(lane + i * 64) * 4) = o;
  }
}

// ---------- out init: out[bt] = w0*bp[e0] + w1*bp[e1] (proj bias, pre-added once) ----------
__global__ void init_out_kernel(const float* __restrict__ tkp, const int* __restrict__ tki,
                                const float* __restrict__ bp, float* __restrict__ out) {
  int bt = (blockIdx.x << 2) | (threadIdx.x >> 6);
  int lane = threadIdx.x & 63;
  int e0 = tki[bt * 2], e1 = tki[bt * 2 + 1];
  float w0 = tkp[bt * 2], w1 = tkp[bt * 2 + 1];
  const f32x4* b0 = (const f32x4*)(bp + (size_t)e0 * C_);
  const f32x4* b1 = (const f32x4*)(bp + (size_t)e1 * C_);
  f32x4* orow = (f32x4*)(out + (size_t)bt * C_);
#pragma unroll
  for (int i = 0; i < 3; i++) {
    int c = lane + i * 64;
    orow[c] = w0 * b0[c] + w1 * b1[c];
  }
}

// ---------- GEMM1 (H-chunked, all experts): S_chunk = silu((X@Wfc+bfc)*(X@Wg+bg)) ----------
// 2-phase dbuf pipeline + LDS XOR swizzle + XCD-aware block swizzle.
// grid = E * 40 * (HC_/128) = 2560 blocks
__global__ __launch_bounds__(256, 2) void gemm_fc_gate(
    const u16* __restrict__ Xd, const u16* __restrict__ WfcT, const u16* __restrict__ WgT,
    const float* __restrict__ bfc, const float* __restrict__ bg, u16* __restrict__ S,
    int hc) {
  __shared__ __align__(16) u16 lds[2][3][128 * 32];
  // XCD swizzle: consecutive work-ids (sharing A panel / expert) land on one XCD
  const int NWG = E_ * 40 * (HC_ / 128);
  int bid0 = blockIdx.x;
  int bid = (bid0 & 7) * (NWG >> 3) + (bid0 >> 3);
  int e = bid / (40 * (HC_ / 128));
  int t = bid % (40 * (HC_ / 128));
  int tm = t / (HC_ / 128), tn = t % (HC_ / 128);
  int tid = threadIdx.x;
  int lane = tid & 63, wv = tid >> 6;
  int wm = wv & 1, wn = wv >> 1;
  int lr = lane & 15, quad = lane >> 4;

  const u16* XdE = Xd + (size_t)e * M_ * C_;
  const u16* B1E = WfcT + ((size_t)e * H_ + (size_t)hc * HC_) * C_;  // [H][C] rows within chunk
  const u16* B2E = WgT + ((size_t)e * H_ + (size_t)hc * HC_) * C_;

  int rhalf = tid >> 2;  // 0..63 = LDS row (and row+64)
  int chunk = tid & 3;
  int swzc = chunk ^ ((rhalf >> 1) & 3);  // source-side XOR so linear DMA lands swizzled
  const u16* gA0 = XdE + (size_t)(tm * 128 + rhalf) * C_ + swzc * 8;
  const u16* gA1 = gA0 + 64 * C_;
  const u16* gB10 = B1E + (size_t)(tn * 128 + rhalf) * C_ + swzc * 8;
  const u16* gB11 = gB10 + 64 * C_;
  const u16* gB20 = B2E + (size_t)(tn * 128 + rhalf) * C_ + swzc * 8;
  const u16* gB21 = gB20 + 64 * C_;
  int ldsW0 = (wv * 16) * 32;        // wave-uniform staging bases
  int ldsW1 = (64 + wv * 16) * 32;

  f32x4 acc1[4][4], acc2[4][4];
#pragma unroll
  for (int i = 0; i < 4; i++)
#pragma unroll
    for (int j = 0; j < 4; j++) {
      acc1[i][j] = (f32x4){0.f, 0.f, 0.f, 0.f};
      acc2[i][j] = (f32x4){0.f, 0.f, 0.f, 0.f};
    }

  const int NK = C_ / 32;  // 24
  int rs = (quad ^ ((lr >> 1) & 3)) * 8;  // swizzled read slot (row-dependent via lr only)

  // prologue: stage tile 0 into buf 0
  {
    gl_lds16(gA0, &lds[0][0][0] + ldsW0);
    gl_lds16(gA1, &lds[0][0][0] + ldsW1);
    gl_lds16(gB10, &lds[0][1][0] + ldsW0);
    gl_lds16(gB11, &lds[0][1][0] + ldsW1);
    gl_lds16(gB20, &lds[0][2][0] + ldsW0);
    gl_lds16(gB21, &lds[0][2][0] + ldsW1);
  }
  __syncthreads();  // vmcnt(0) drain: tile 0 resident

  int cur = 0;
  for (int kt = 0; kt < NK; kt++) {
    // issue next tile's DMA first (overlaps with this tile's ds_read+MFMA)
    if (kt + 1 < NK) {
      int ko = (kt + 1) * 32;
      int nb = cur ^ 1;
      gl_lds16(gA0 + ko, &lds[nb][0][0] + ldsW0);
      gl_lds16(gA1 + ko, &lds[nb][0][0] + ldsW1);
      gl_lds16(gB10 + ko, &lds[nb][1][0] + ldsW0);
      gl_lds16(gB11 + ko, &lds[nb][1][0] + ldsW1);
      gl_lds16(gB20 + ko, &lds[nb][2][0] + ldsW0);
      gl_lds16(gB21 + ko, &lds[nb][2][0] + ldsW1);
    }
    bf16x8 af[4], b1f[4], b2f[4];
#pragma unroll
    for (int i = 0; i < 4; i++) {
      af[i] = ldfrag(&lds[cur][0][0] + (wm * 64 + i * 16 + lr) * 32 + rs);
      b1f[i] = ldfrag(&lds[cur][1][0] + (wn * 64 + i * 16 + lr) * 32 + rs);
      b2f[i] = ldfrag(&lds[cur][2][0] + (wn * 64 + i * 16 + lr) * 32 + rs);
    }
#pragma unroll
    for (int i = 0; i < 4; i++)
#pragma unroll
      for (int j = 0; j < 4; j++) {
        acc1[i][j] = __builtin_amdgcn_mfma_f32_16x16x32_bf16(af[i], b1f[j], acc1[i][j], 0, 0, 0);
        acc2[i][j] = __builtin_amdgcn_mfma_f32_16x16x32_bf16(af[i], b2f[j], acc2[i][j], 0, 0, 0);
      }
    // one barrier per K-step: its vmcnt(0) drain = next tile resident;
    // rendezvous = everyone done reading cur (safe to overwrite next iter)
    __syncthreads();
    cur ^= 1;
  }

  u16* Se = S + (size_t)e * M_ * HC_;
  const float* bfcE = bfc + (size_t)e * H_ + (size_t)hc * HC_;
  const float* bgE = bg + (size_t)e * H_ + (size_t)hc * HC_;
  int col0 = tn * 128 + wn * 64 + lr;  // local column within chunk
  int row0 = tm * 128 + wm * 64 + quad * 4;
#pragma unroll
  for (int j = 0; j < 4; j++) {
    int col = col0 + j * 16;
    float bf_ = bfcE[col], bg_ = bgE[col];
#pragma unroll
    for (int i = 0; i < 4; i++) {
      int row = row0 + i * 16;
#pragma unroll
      for (int r = 0; r < 4; r++) {
        float h = acc1[i][j][r] + bf_;
        float g = acc2[i][j][r] + bg_;
        float z = h * g;
        float sv = z / (1.f + __expf(-z));  // silu
        Se[(size_t)(row + r) * HC_ + col] = f2bf(sv);
      }
    }
  }
}

// ---------- GEMM2 (H-chunked, all experts): partial O scatter-added into out ----------
// grid = E * 40 * 6 = 1920 blocks. K = HC_ per chunk. Same pipeline/swizzles.
__global__ __launch_bounds__(256, 3) void gemm_proj_scatter(
    const u16* __restrict__ S, const u16* __restrict__ WpT,
    const int* __restrict__ invt, const float* __restrict__ tkp,
    const int* __restrict__ tki, const int* __restrict__ ovfCnt,
    const int2* __restrict__ ovf, float* __restrict__ out, int hc) {
  __shared__ __align__(16) u16 lds[2][2][128 * 32];
  const int NWG = E_ * 40 * 6;
  int bid0 = blockIdx.x;
  int bid = (bid0 & 7) * (NWG >> 3) + (bid0 >> 3);
  int e = bid / (40 * 6);
  int t = bid % (40 * 6);
  int tm = t / 6, tn = t % 6;
  int tid = threadIdx.x;
  int lane = tid & 63, wv = tid >> 6;
  int wm = wv & 1, wn = wv >> 1;
  int lr = lane & 15, quad = lane >> 4;

  const u16* SE = S + (size_t)e * M_ * HC_;                     // [M][HC] rows
  const u16* BE = WpT + (size_t)e * C_ * H_ + (size_t)hc * HC_; // [C][H], k-offset into chunk

  int rhalf = tid >> 2;
  int chunk = tid & 3;
  int swzc = chunk ^ ((rhalf >> 1) & 3);
  const u16* gA0 = SE + (size_t)(tm * 128 + rhalf) * HC_ + swzc * 8;
  const u16* gA1 = gA0 + 64 * HC_;
  const u16* gB0 = BE + (size_t)(tn * 128 + rhalf) * H_ + swzc * 8;
  const u16* gB1 = gB0 + 64 * H_;
  int ldsW0 = (wv * 16) * 32;
  int ldsW1 = (64 + wv * 16) * 32;

  f32x4 acc[4][4];
#pragma unroll
  for (int i = 0; i < 4; i++)
#pragma unroll
    for (int j = 0; j < 4; j++) acc[i][j] = (f32x4){0.f, 0.f, 0.f, 0.f};

  const int NK = HC_ / 32;  // 32
  int rs = (quad ^ ((lr >> 1) & 3)) * 8;

  {
    gl_lds16(gA0, &lds[0][0][0] + ldsW0);
    gl_lds16(gA1, &lds[0][0][0] + ldsW1);
    gl_lds16(gB0, &lds[0][1][0] + ldsW0);
    gl_lds16(gB1, &lds[0][1][0] + ldsW1);
  }
  __syncthreads();

  int cur = 0;
  for (int kt = 0; kt < NK; kt++) {
    if (kt + 1 < NK) {
      int ko = (kt + 1) * 32;
      int nb = cur ^ 1;
      gl_lds16(gA0 + ko, &lds[nb][0][0] + ldsW0);
      gl_lds16(gA1 + ko, &lds[nb][0][0] + ldsW1);
      gl_lds16(gB0 + ko, &lds[nb][1][0] + ldsW0);
      gl_lds16(gB1 + ko, &lds[nb][1][0] + ldsW1);
    }
    bf16x8 af[4], bf[4];
#pragma unroll
    for (int i = 0; i < 4; i++) {
      af[i] = ldfrag(&lds[cur][0][0] + (wm * 64 + i * 16 + lr) * 32 + rs);
      bf[i] = ldfrag(&lds[cur][1][0] + (wn * 64 + i * 16 + lr) * 32 + rs);
    }
#pragma unroll
    for (int i = 0; i < 4; i++)
#pragma unroll
      for (int j = 0; j < 4; j++)
        acc[i][j] = __builtin_amdgcn_mfma_f32_16x16x32_bf16(af[i], bf[j], acc[i][j], 0, 0, 0);
    __syncthreads();
    cur ^= 1;
  }

  // epilogue: weighted scatter-add into out (bias already in out via init_out)
  int col0 = tn * 128 + wn * 64 + lr;
  int row0 = tm * 128 + wm * 64 + quad * 4;
  const int* invtE = invt + e * M_;
#pragma unroll
  for (int i = 0; i < 4; i++) {
#pragma unroll
    for (int r = 0; r < 4; r++) {
      int re = row0 + i * 16 + r;
      int g = invtE[re];  // row-uniform per quad -> branch is quad-uniform
      if (g >= 0) {
        float w = tkp[g];
        float* orow = out + (size_t)(g >> 1) * C_;
#pragma unroll
        for (int j = 0; j < 4; j++)
          atomicAdd(orow + col0 + j * 16, w * acc[i][j][r]);
      }
    }
  }
  // dropped tokens gather clamped row CAP_-1 (jax clip semantics). Blocks whose tile
  // contains row (b, CAP_-1) (tm%5==4, local row 127 -> wm=1,quad=3,i=3,r=3) also add
  // that row's partial for each matching overflow entry. n==0 in practice.
  if (wm == 1 && quad == 3 && (tm % 5) == 4) {
    int b = tm / 5;
    int nov = *ovfCnt;
    if (nov > OVF_MAX_) nov = OVF_MAX_;
    for (int o = 0; o < nov; o++) {
      int2 en = ovf[o];
      int gw2 = en.x * 2 + en.y;
      if (tki[gw2] == e && (en.x >> 11) == b) {
        float w = tkp[gw2];
        float* orow = out + (size_t)en.x * C_;
#pragma unroll
        for (int j = 0; j < 4; j++)
          atomicAdd(orow + col0 + j * 16, w * acc[3][j][3]);
      }
    }
  }
}

extern "C" void kernel_launch(void* const* d_in, const int* in_sizes, int n_in,
                              void* d_out, int out_size, void* d_ws, size_t ws_size,
                              hipStream_t stream) {
  (void)in_sizes; (void)n_in; (void)out_size; (void)ws_size;
  const float* x = (const float*)d_in[0];
  const float* w_router = (const float*)d_in[1];
  const float* b_router = (const float*)d_in[2];
  const float* w_c_fc = (const float*)d_in[3];
  const float* b_c_fc = (const float*)d_in[4];
  const float* w_gate = (const float*)d_in[5];
  const float* b_gate = (const float*)d_in[6];
  const float* w_c_proj = (const float*)d_in[7];
  const float* b_c_proj = (const float*)d_in[8];
  float* out = (float*)d_out;

  char* p = (char*)d_ws;
  auto alloc = [&](size_t n) { char* r = p; p += (n + 255) & ~(size_t)255; return r; };
  const size_t WN = (size_t)E_ * C_ * H_;
  u16* WfcT = (u16*)alloc(WN * 2);
  u16* WgT = (u16*)alloc(WN * 2);
  u16* WpT = (u16*)alloc(WN * 2);
  u16* Xd = (u16*)alloc((size_t)E_ * M_ * C_ * 2);
  float* tkp = (float*)alloc((size_t)B_ * T_ * 2 * 4);
  int* tki = (int*)alloc((size_t)B_ * T_ * 2 * 4);
  int* pos = (int*)alloc((size_t)B_ * T_ * 2 * 4);
  int* invt = (int*)alloc((size_t)E_ * M_ * 4);
  int* ovfCnt = (int*)alloc(4);
  int2* ovf = (int2*)alloc((size_t)OVF_MAX_ * 8);
  u16* S = (u16*)alloc((size_t)E_ * M_ * HC_ * 2);
  // total ~260.9 MB; previous g=1 layout proved ws >= 271 MB, so this fits.

  dim3 blk(256);
  // weights -> bf16, transposed to [N][K]
  wconv_transpose<<<dim3(H_ / 32, C_ / 32, E_), blk, 0, stream>>>(w_c_fc, WfcT, C_, H_);
  wconv_transpose<<<dim3(H_ / 32, C_ / 32, E_), blk, 0, stream>>>(w_gate, WgT, C_, H_);
  wconv_transpose<<<dim3(C_ / 32, H_ / 32, E_), blk, 0, stream>>>(w_c_proj, WpT, H_, C_);

  router_kernel<<<dim3(B_ * T_ / 4), blk, 0, stream>>>(x, w_router, b_router, tkp, tki);
  pos_kernel<<<dim3(B_), blk, 0, stream>>>(tki, pos);
  clear_kernel<<<dim3(E_ * M_ / 256), blk, 0, stream>>>(invt, ovfCnt);
  dispatch_kernel<<<dim3(B_ * T_ * K_ / 4), blk, 0, stream>>>(x, tki, pos, Xd, invt, ovfCnt, ovf);
  init_out_kernel<<<dim3(B_ * T_ / 4), blk, 0, stream>>>(tkp, tki, b_c_proj, out);

  // H-chunked grouped GEMMs: every dispatch spans all 8 experts (2560 / 1920 blocks)
  for (int hc = 0; hc < NCHUNK_; hc++) {
    gemm_fc_gate<<<dim3(E_ * 40 * (HC_ / 128)), blk, 0, stream>>>(
        Xd, WfcT, WgT, b_c_fc, b_gate, S, hc);
    gemm_proj_scatter<<<dim3(E_ * 40 * 6), blk, 0, stream>>>(
        S, WpT, invt, tkp, tki, ovfCnt, ovf, out, hc);
  }
}

// Round 3
// 1104.594 us; speedup vs baseline: 1.2758x; 1.0415x over previous
//
#include <hip/hip_runtime.h>

typedef unsigned short u16;
typedef unsigned int u32;
using u16x4 = __attribute__((ext_vector_type(4))) u16;
using u16x8 = __attribute__((ext_vector_type(8))) u16;
using bf16x8 = __attribute__((ext_vector_type(8))) __bf16;
using f32x4 = __attribute__((ext_vector_type(4))) float;

#define B_ 8
#define T_ 2048
#define C_ 768
#define E_ 8
#define K_ 2
#define H_ 3072
#define CAP_ 640
#define M_ (B_ * CAP_) /* 5120 rows per expert */
#define HC_ 1024       /* H chunk: S_chunk = E*M*HC bf16 = 83.9 MB */
#define NCHUNK_ (H_ / HC_)
#define OVF_MAX_ 32768

__device__ __forceinline__ u16 f2bf(float x) {
  u32 u = __float_as_uint(x);
  u32 r = (u + 0x7FFFu + ((u >> 16) & 1u)) >> 16;  // RNE
  return (u16)r;
}
__device__ __forceinline__ float bf2f(u16 v) { return __uint_as_float(((u32)v) << 16); }

__device__ __forceinline__ void gl_lds16(const u16* g, u16* l) {
  __builtin_amdgcn_global_load_lds((const __attribute__((address_space(1))) u32*)g,
                                   (__attribute__((address_space(3))) u32*)l, 16, 0, 0);
}
__device__ __forceinline__ bf16x8 ldfrag(const u16* p) {
  return __builtin_bit_cast(bf16x8, *(const u16x8*)p);
}

// ---------- weight fp32 -> bf16 transpose:  in [E][R][Cc] -> out [E][Cc][R] ----------
__global__ void wconv_transpose(const float* __restrict__ in, u16* __restrict__ out,
                                int R, int Cc) {
  __shared__ float tile[32][33];
  const float* inE = in + (size_t)blockIdx.z * R * Cc;
  u16* outE = out + (size_t)blockIdx.z * R * Cc;
  int tx = threadIdx.x & 31, ty = threadIdx.x >> 5;  // 32 x 8
  int r0 = blockIdx.y * 32, c0 = blockIdx.x * 32;
#pragma unroll
  for (int j = 0; j < 4; j++)
    tile[ty + j * 8][tx] = inE[(size_t)(r0 + ty + j * 8) * Cc + (c0 + tx)];
  __syncthreads();
#pragma unroll
  for (int j = 0; j < 4; j++)
    outE[(size_t)(c0 + ty + j * 8) * R + (r0 + tx)] = f2bf(tile[tx][ty + j * 8]);
}

// ---------- router: logits, softmax, top-2 (fp64 accumulate; tie -> lower index) ----------
__global__ void router_kernel(const float* __restrict__ x, const float* __restrict__ wr,
                              const float* __restrict__ br, float* __restrict__ tkp,
                              int* __restrict__ tki) {
  int bt = (blockIdx.x << 2) | (threadIdx.x >> 6);  // token index b*T+t
  int lane = threadIdx.x & 63;
  const float* xr = x + (size_t)bt * C_;
  double acc[E_];
#pragma unroll
  for (int e = 0; e < E_; e++) acc[e] = 0.0;
#pragma unroll
  for (int i = 0; i < C_ / 64; i++) {
    int c = lane + i * 64;
    float xv = xr[c];
    const float* w = wr + c * E_;
#pragma unroll
    for (int e = 0; e < E_; e++) acc[e] += (double)xv * (double)w[e];
  }
#pragma unroll
  for (int off = 32; off > 0; off >>= 1) {
#pragma unroll
    for (int e = 0; e < E_; e++) acc[e] += __shfl_xor(acc[e], off);
  }
  if (lane == 0) {
    double lg[E_];
#pragma unroll
    for (int e = 0; e < E_; e++) lg[e] = acc[e] + (double)br[e];
    int i0 = 0;
#pragma unroll
    for (int e = 1; e < E_; e++) if (lg[e] > lg[i0]) i0 = e;
    int i1 = (i0 == 0) ? 1 : 0;
#pragma unroll
    for (int e = 0; e < E_; e++) if (e != i0 && lg[e] > lg[i1]) i1 = e;
    double mx = lg[i0], s = 0.0, pv[E_];
#pragma unroll
    for (int e = 0; e < E_; e++) { pv[e] = exp(lg[e] - mx); s += pv[e]; }
    tkp[bt * 2 + 0] = (float)(pv[i0] / s);
    tkp[bt * 2 + 1] = (float)(pv[i1] / s);
    tki[bt * 2 + 0] = i0;
    tki[bt * 2 + 1] = i1;
  }
}

// ---------- slot positions: parallel 8-way counted scan, one block per b ----------
__global__ void pos_kernel(const int* __restrict__ tki, int* __restrict__ pos) {
  __shared__ int sc[256][9];  // +1 pad: avoid 8-way bank conflict
  int b = blockIdx.x;
  int tid = threadIdx.x;
  const int* tib = tki + (size_t)b * T_ * 2;
  int* pb = pos + (size_t)b * T_ * 2;
  int ids[16];
  int cnt[E_];
#pragma unroll
  for (int e = 0; e < E_; e++) cnt[e] = 0;
#pragma unroll
  for (int j = 0; j < 16; j++) {
    int i = tid * 16 + j;
    int k = i >> 11, t = i & (T_ - 1);  // k-major
    int id = tib[t * 2 + k];
    ids[j] = id;
#pragma unroll
    for (int e = 0; e < E_; e++) cnt[e] += (id == e);
  }
#pragma unroll
  for (int e = 0; e < E_; e++) sc[tid][e] = cnt[e];
  __syncthreads();
  for (int off = 1; off < 256; off <<= 1) {
    int v[E_];
    if (tid >= off) {
#pragma unroll
      for (int e = 0; e < E_; e++) v[e] = sc[tid - off][e];
    }
    __syncthreads();
    if (tid >= off) {
#pragma unroll
      for (int e = 0; e < E_; e++) sc[tid][e] += v[e];
    }
    __syncthreads();
  }
  int base[E_];
#pragma unroll
  for (int e = 0; e < E_; e++) base[e] = (tid > 0) ? sc[tid - 1][e] : 0;
#pragma unroll
  for (int j = 0; j < 16; j++) {
    int i = tid * 16 + j;
    int k = i >> 11, t = i & (T_ - 1);
    int id = ids[j];
    int p = 0;
#pragma unroll
    for (int e = 0; e < E_; e++) p += (id == e) ? base[e] : 0;
    pb[t * 2 + k] = p;
#pragma unroll
    for (int e = 0; e < E_; e++) base[e] += (id == e);
  }
}

// ---------- clear inverse map + overflow counter (must precede dispatch) ----------
__global__ void clear_kernel(int* __restrict__ invt, int* __restrict__ ovfCnt) {
  int i = blockIdx.x * 256 + threadIdx.x;  // grid covers exactly E_*M_
  invt[i] = -1;
  if (i == 0) *ovfCnt = 0;
}

// ---------- dispatch: x row -> bf16 expert buffer [E][M_][C_] + inverse slot->token map ----------
__global__ void dispatch_kernel(const float* __restrict__ x, const int* __restrict__ tki,
                                const int* __restrict__ pos, u16* __restrict__ Xd,
                                int* __restrict__ invt, int* __restrict__ ovfCnt,
                                int2* __restrict__ ovf) {
  int gw = (blockIdx.x << 2) | (threadIdx.x >> 6);  // (b*T+t)*2 + k
  int lane = threadIdx.x & 63;
  int bt = gw >> 1;
  int b = bt >> 11;
  int e = tki[gw];
  int p = pos[gw];
  if (p >= CAP_) {  // capacity drop: record for exact clamp-gather handling
    if (lane == 0) {
      int idx = atomicAdd(ovfCnt, 1);
      if (idx < OVF_MAX_) ovf[idx] = make_int2(bt, gw & 1);
    }
    return;
  }
  size_t row = (size_t)e * M_ + (size_t)b * CAP_ + p;
  if (lane == 0) invt[row] = gw;  // owner (token,slot) of this expert row
  const f32x4* src = (const f32x4*)(x + (size_t)bt * C_);
  u16* dst = Xd + row * C_;
#pragma unroll
  for (int i = 0; i < 3; i++) {
    f32x4 v = src[lane + i * 64];
    u16x4 o;
    o.x = f2bf(v.x); o.y = f2bf(v.y); o.z = f2bf(v.z); o.w = f2bf(v.w);
    *(u16x4*)(dst + (size_t)(lane + i * 64) * 4) = o;
  }
}

// ---------- out init: out[bt] = w0*bp[e0] + w1*bp[e1] (proj bias, pre-added once) ----------
__global__ void init_out_kernel(const float* __restrict__ tkp, const int* __restrict__ tki,
                                const float* __restrict__ bp, float* __restrict__ out) {
  int bt = (blockIdx.x << 2) | (threadIdx.x >> 6);
  int lane = threadIdx.x & 63;
  int e0 = tki[bt * 2], e1 = tki[bt * 2 + 1];
  float w0 = tkp[bt * 2], w1 = tkp[bt * 2 + 1];
  const f32x4* b0 = (const f32x4*)(bp + (size_t)e0 * C_);
  const f32x4* b1 = (const f32x4*)(bp + (size_t)e1 * C_);
  f32x4* orow = (f32x4*)(out + (size_t)bt * C_);
#pragma unroll
  for (int i = 0; i < 3; i++) {
    int c = lane + i * 64;
    orow[c] = w0 * b0[c] + w1 * b1[c];
  }
}

// ---------- GEMM1 (H-chunked, all experts): S_chunk = silu((X@Wfc+bfc)*(X@Wg+bg)) ----------
// Depth-2 counted-vmcnt pipeline (3 LDS bufs, raw s_barrier, vmcnt never 0 mid-loop)
// + LDS XOR swizzle + XCD-aware block swizzle. grid = E * 40 * (HC_/128) = 2560 blocks
__global__ __launch_bounds__(256, 2) void gemm_fc_gate(
    const u16* __restrict__ Xd, const u16* __restrict__ WfcT, const u16* __restrict__ WgT,
    const float* __restrict__ bfc, const float* __restrict__ bg, u16* __restrict__ S,
    int hc) {
  __shared__ __align__(16) u16 lds[3][3][128 * 32];  // 72 KB -> 2 blocks/CU
  const int NWG = E_ * 40 * (HC_ / 128);
  int bid0 = blockIdx.x;
  int bid = (bid0 & 7) * (NWG >> 3) + (bid0 >> 3);  // XCD swizzle (NWG%8==0)
  int e = bid / (40 * (HC_ / 128));
  int t = bid % (40 * (HC_ / 128));
  int tm = t / (HC_ / 128), tn = t % (HC_ / 128);
  int tid = threadIdx.x;
  int lane = tid & 63, wv = tid >> 6;
  int wm = wv & 1, wn = wv >> 1;
  int lr = lane & 15, quad = lane >> 4;

  const u16* XdE = Xd + (size_t)e * M_ * C_;
  const u16* B1E = WfcT + ((size_t)e * H_ + (size_t)hc * HC_) * C_;  // [H][C] rows within chunk
  const u16* B2E = WgT + ((size_t)e * H_ + (size_t)hc * HC_) * C_;

  int rhalf = tid >> 2;  // 0..63 = LDS row (and row+64)
  int chunk = tid & 3;
  int swzc = chunk ^ ((rhalf >> 1) & 3);  // source-side XOR so linear DMA lands swizzled
  const u16* gA0 = XdE + (size_t)(tm * 128 + rhalf) * C_ + swzc * 8;
  const u16* gA1 = gA0 + 64 * C_;
  const u16* gB10 = B1E + (size_t)(tn * 128 + rhalf) * C_ + swzc * 8;
  const u16* gB11 = gB10 + 64 * C_;
  const u16* gB20 = B2E + (size_t)(tn * 128 + rhalf) * C_ + swzc * 8;
  const u16* gB21 = gB20 + 64 * C_;
  int ldsW0 = (wv * 16) * 32;  // wave-uniform staging bases
  int ldsW1 = (64 + wv * 16) * 32;

  auto stage = [&](int kt, int b) {
    int ko = kt * 32;
    gl_lds16(gA0 + ko, &lds[b][0][0] + ldsW0);
    gl_lds16(gA1 + ko, &lds[b][0][0] + ldsW1);
    gl_lds16(gB10 + ko, &lds[b][1][0] + ldsW0);
    gl_lds16(gB11 + ko, &lds[b][1][0] + ldsW1);
    gl_lds16(gB20 + ko, &lds[b][2][0] + ldsW0);
    gl_lds16(gB21 + ko, &lds[b][2][0] + ldsW1);
  };

  f32x4 acc1[4][4], acc2[4][4];
#pragma unroll
  for (int i = 0; i < 4; i++)
#pragma unroll
    for (int j = 0; j < 4; j++) {
      acc1[i][j] = (f32x4){0.f, 0.f, 0.f, 0.f};
      acc2[i][j] = (f32x4){0.f, 0.f, 0.f, 0.f};
    }

  const int NK = C_ / 32;  // 24
  int rs = (quad ^ ((lr >> 1) & 3)) * 8;  // swizzled read slot

  // prologue: tiles 0,1 in flight (12 loads/wave)
  stage(0, 0);
  stage(1, 1);

  int cur = 0;
  for (int kt = 0; kt < NK; kt++) {
    // wait ONLY tile kt (6 loads); tile kt+1's 6 stay in flight across the barrier
    if (kt < NK - 1) asm volatile("s_waitcnt vmcnt(6)" ::: "memory");
    else             asm volatile("s_waitcnt vmcnt(0)" ::: "memory");
    __builtin_amdgcn_s_barrier();
    __builtin_amdgcn_sched_barrier(0);  // pin: nothing moves above the barrier
    // stage tile kt+2 into the buffer tile kt-1 used (all waves done reading it)
    if (kt + 2 < NK) {
      int nb = cur + 2; if (nb >= 3) nb -= 3;
      stage(kt + 2, nb);
    }
    bf16x8 af[4], b1f[4], b2f[4];
#pragma unroll
    for (int i = 0; i < 4; i++) {
      af[i] = ldfrag(&lds[cur][0][0] + (wm * 64 + i * 16 + lr) * 32 + rs);
      b1f[i] = ldfrag(&lds[cur][1][0] + (wn * 64 + i * 16 + lr) * 32 + rs);
      b2f[i] = ldfrag(&lds[cur][2][0] + (wn * 64 + i * 16 + lr) * 32 + rs);
    }
    __builtin_amdgcn_s_setprio(1);
#pragma unroll
    for (int i = 0; i < 4; i++)
#pragma unroll
      for (int j = 0; j < 4; j++) {
        acc1[i][j] = __builtin_amdgcn_mfma_f32_16x16x32_bf16(af[i], b1f[j], acc1[i][j], 0, 0, 0);
        acc2[i][j] = __builtin_amdgcn_mfma_f32_16x16x32_bf16(af[i], b2f[j], acc2[i][j], 0, 0, 0);
      }
    __builtin_amdgcn_s_setprio(0);
    cur = cur + 1; if (cur >= 3) cur -= 3;
  }

  u16* Se = S + (size_t)e * M_ * HC_;
  const float* bfcE = bfc + (size_t)e * H_ + (size_t)hc * HC_;
  const float* bgE = bg + (size_t)e * H_ + (size_t)hc * HC_;
  int col0 = tn * 128 + wn * 64 + lr;  // local column within chunk
  int row0 = tm * 128 + wm * 64 + quad * 4;
#pragma unroll
  for (int j = 0; j < 4; j++) {
    int col = col0 + j * 16;
    float bf_ = bfcE[col], bg_ = bgE[col];
#pragma unroll
    for (int i = 0; i < 4; i++) {
      int row = row0 + i * 16;
#pragma unroll
      for (int r = 0; r < 4; r++) {
        float h = acc1[i][j][r] + bf_;
        float g = acc2[i][j][r] + bg_;
        float z = h * g;
        float sv = z / (1.f + __expf(-z));  // silu
        Se[(size_t)(row + r) * HC_ + col] = f2bf(sv);
      }
    }
  }
}

// ---------- GEMM2 (H-chunked, all experts): partial O scatter-added into out ----------
// grid = E * 40 * 6 = 1920 blocks. K = HC_ per chunk. Same pipeline/swizzles.
__global__ __launch_bounds__(256, 3) void gemm_proj_scatter(
    const u16* __restrict__ S, const u16* __restrict__ WpT,
    const int* __restrict__ invt, const float* __restrict__ tkp,
    const int* __restrict__ tki, const int* __restrict__ ovfCnt,
    const int2* __restrict__ ovf, float* __restrict__ out, int hc) {
  __shared__ __align__(16) u16 lds[3][2][128 * 32];  // 48 KB -> 3 blocks/CU
  const int NWG = E_ * 40 * 6;
  int bid0 = blockIdx.x;
  int bid = (bid0 & 7) * (NWG >> 3) + (bid0 >> 3);
  int e = bid / (40 * 6);
  int t = bid % (40 * 6);
  int tm = t / 6, tn = t % 6;
  int tid = threadIdx.x;
  int lane = tid & 63, wv = tid >> 6;
  int wm = wv & 1, wn = wv >> 1;
  int lr = lane & 15, quad = lane >> 4;

  const u16* SE = S + (size_t)e * M_ * HC_;                     // [M][HC] rows
  const u16* BE = WpT + (size_t)e * C_ * H_ + (size_t)hc * HC_; // [C][H], k-offset into chunk

  int rhalf = tid >> 2;
  int chunk = tid & 3;
  int swzc = chunk ^ ((rhalf >> 1) & 3);
  const u16* gA0 = SE + (size_t)(tm * 128 + rhalf) * HC_ + swzc * 8;
  const u16* gA1 = gA0 + 64 * HC_;
  const u16* gB0 = BE + (size_t)(tn * 128 + rhalf) * H_ + swzc * 8;
  const u16* gB1 = gB0 + 64 * H_;
  int ldsW0 = (wv * 16) * 32;
  int ldsW1 = (64 + wv * 16) * 32;

  auto stage = [&](int kt, int b) {
    int ko = kt * 32;
    gl_lds16(gA0 + ko, &lds[b][0][0] + ldsW0);
    gl_lds16(gA1 + ko, &lds[b][0][0] + ldsW1);
    gl_lds16(gB0 + ko, &lds[b][1][0] + ldsW0);
    gl_lds16(gB1 + ko, &lds[b][1][0] + ldsW1);
  };

  f32x4 acc[4][4];
#pragma unroll
  for (int i = 0; i < 4; i++)
#pragma unroll
    for (int j = 0; j < 4; j++) acc[i][j] = (f32x4){0.f, 0.f, 0.f, 0.f};

  const int NK = HC_ / 32;  // 32
  int rs = (quad ^ ((lr >> 1) & 3)) * 8;

  stage(0, 0);
  stage(1, 1);

  int cur = 0;
  for (int kt = 0; kt < NK; kt++) {
    if (kt < NK - 1) asm volatile("s_waitcnt vmcnt(4)" ::: "memory");
    else             asm volatile("s_waitcnt vmcnt(0)" ::: "memory");
    __builtin_amdgcn_s_barrier();
    __builtin_amdgcn_sched_barrier(0);
    if (kt + 2 < NK) {
      int nb = cur + 2; if (nb >= 3) nb -= 3;
      stage(kt + 2, nb);
    }
    bf16x8 af[4], bf[4];
#pragma unroll
    for (int i = 0; i < 4; i++) {
      af[i] = ldfrag(&lds[cur][0][0] + (wm * 64 + i * 16 + lr) * 32 + rs);
      bf[i] = ldfrag(&lds[cur][1][0] + (wn * 64 + i * 16 + lr) * 32 + rs);
    }
    __builtin_amdgcn_s_setprio(1);
#pragma unroll
    for (int i = 0; i < 4; i++)
#pragma unroll
      for (int j = 0; j < 4; j++)
        acc[i][j] = __builtin_amdgcn_mfma_f32_16x16x32_bf16(af[i], bf[j], acc[i][j], 0, 0, 0);
    __builtin_amdgcn_s_setprio(0);
    cur = cur + 1; if (cur >= 3) cur -= 3;
  }

  // epilogue: weighted scatter-add into out (bias already in out via init_out)
  int col0 = tn * 128 + wn * 64 + lr;
  int row0 = tm * 128 + wm * 64 + quad * 4;
  const int* invtE = invt + e * M_;
#pragma unroll
  for (int i = 0; i < 4; i++) {
#pragma unroll
    for (int r = 0; r < 4; r++) {
      int re = row0 + i * 16 + r;
      int g = invtE[re];  // row-uniform per quad -> branch is quad-uniform
      if (g >= 0) {
        float w = tkp[g];
        float* orow = out + (size_t)(g >> 1) * C_;
#pragma unroll
        for (int j = 0; j < 4; j++)
          atomicAdd(orow + col0 + j * 16, w * acc[i][j][r]);
      }
    }
  }
  // dropped tokens gather clamped row CAP_-1 (jax clip semantics). Blocks whose tile
  // contains row (b, CAP_-1) (tm%5==4, local row 127 -> wm=1,quad=3,i=3,r=3) also add
  // that row's partial for each matching overflow entry. n==0 in practice.
  if (wm == 1 && quad == 3 && (tm % 5) == 4) {
    int b = tm / 5;
    int nov = *ovfCnt;
    if (nov > OVF_MAX_) nov = OVF_MAX_;
    for (int o = 0; o < nov; o++) {
      int2 en = ovf[o];
      int gw2 = en.x * 2 + en.y;
      if (tki[gw2] == e && (en.x >> 11) == b) {
        float w = tkp[gw2];
        float* orow = out + (size_t)en.x * C_;
#pragma unroll
        for (int j = 0; j < 4; j++)
          atomicAdd(orow + col0 + j * 16, w * acc[3][j][3]);
      }
    }
  }
}

extern "C" void kernel_launch(void* const* d_in, const int* in_sizes, int n_in,
                              void* d_out, int out_size, void* d_ws, size_t ws_size,
                              hipStream_t stream) {
  (void)in_sizes; (void)n_in; (void)out_size; (void)ws_size;
  const float* x = (const float*)d_in[0];
  const float* w_router = (const float*)d_in[1];
  const float* b_router = (const float*)d_in[2];
  const float* w_c_fc = (const float*)d_in[3];
  const float* b_c_fc = (const float*)d_in[4];
  const float* w_gate = (const float*)d_in[5];
  const float* b_gate = (const float*)d_in[6];
  const float* w_c_proj = (const float*)d_in[7];
  const float* b_c_proj = (const float*)d_in[8];
  float* out = (float*)d_out;

  char* p = (char*)d_ws;
  auto alloc = [&](size_t n) { char* r = p; p += (n + 255) & ~(size_t)255; return r; };
  const size_t WN = (size_t)E_ * C_ * H_;
  u16* WfcT = (u16*)alloc(WN * 2);
  u16* WgT = (u16*)alloc(WN * 2);
  u16* WpT = (u16*)alloc(WN * 2);
  u16* Xd = (u16*)alloc((size_t)E_ * M_ * C_ * 2);
  float* tkp = (float*)alloc((size_t)B_ * T_ * 2 * 4);
  int* tki = (int*)alloc((size_t)B_ * T_ * 2 * 4);
  int* pos = (int*)alloc((size_t)B_ * T_ * 2 * 4);
  int* invt = (int*)alloc((size_t)E_ * M_ * 4);
  int* ovfCnt = (int*)alloc(4);
  int2* ovf = (int2*)alloc((size_t)OVF_MAX_ * 8);
  u16* S = (u16*)alloc((size_t)E_ * M_ * HC_ * 2);
  // total ~260.9 MB; previous g=1 layout proved ws >= 271 MB, so this fits.

  dim3 blk(256);
  // weights -> bf16, transposed to [N][K]
  wconv_transpose<<<dim3(H_ / 32, C_ / 32, E_), blk, 0, stream>>>(w_c_fc, WfcT, C_, H_);
  wconv_transpose<<<dim3(H_ / 32, C_ / 32, E_), blk, 0, stream>>>(w_gate, WgT, C_, H_);
  wconv_transpose<<<dim3(C_ / 32, H_ / 32, E_), blk, 0, stream>>>(w_c_proj, WpT, H_, C_);

  router_kernel<<<dim3(B_ * T_ / 4), blk, 0, stream>>>(x, w_router, b_router, tkp, tki);
  pos_kernel<<<dim3(B_), blk, 0, stream>>>(tki, pos);
  clear_kernel<<<dim3(E_ * M_ / 256), blk, 0, stream>>>(invt, ovfCnt);
  dispatch_kernel<<<dim3(B_ * T_ * K_ / 4), blk, 0, stream>>>(x, tki, pos, Xd, invt, ovfCnt, ovf);
  init_out_kernel<<<dim3(B_ * T_ / 4), blk, 0, stream>>>(tkp, tki, b_c_proj, out);

  // H-chunked grouped GEMMs: every dispatch spans all 8 experts (2560 / 1920 blocks)
  for (int hc = 0; hc < NCHUNK_; hc++) {
    gemm_fc_gate<<<dim3(E_ * 40 * (HC_ / 128)), blk, 0, stream>>>(
        Xd, WfcT, WgT, b_c_fc, b_gate, S, hc);
    gemm_proj_scatter<<<dim3(E_ * 40 * 6), blk, 0, stream>>>(
        S, WpT, invt, tkp, tki, ovfCnt, ovf, out, hc);
  }
}